// Round 1
// 152.489 us; speedup vs baseline: 1.0324x; 1.0324x over previous
//
#include <hip/hip_runtime.h>
#include <hip/hip_bf16.h>
#include <stdint.h>

#define N_DIM 1024
#define DEPTH 2
#define ABCD_TOTAL 4092   // 2*(1024+512+...+2)

typedef __attribute__((ext_vector_type(8))) short short8;   // 8 bf16 (4 VGPRs)
typedef __attribute__((ext_vector_type(4))) float floatx4;  // MFMA accumulator
typedef __attribute__((ext_vector_type(4))) float f4;       // {re0,im0,re1,im1}

__device__ __forceinline__ f4 cmul(float cr, float ci, f4 v) {
    f4 r;
    r[0] = cr * v[0] - ci * v[1];
    r[1] = cr * v[1] + ci * v[0];
    r[2] = cr * v[2] - ci * v[3];
    r[3] = cr * v[3] + ci * v[2];
    return r;
}

// ---------------------------------------------------------------------------
// Kernel 1 (fused): blocks [0,512) build W; blocks [512, 512+8192) cast x.
// (unchanged from previous round — verified)
// ---------------------------------------------------------------------------
__global__ __launch_bounds__(256) void build_and_cast(
    const float* __restrict__ perm_logit,  // (2,3)
    const float* __restrict__ abcd,        // (2,4092,2)
    const float* __restrict__ x,           // (16384,1024)
    __hip_bfloat16* __restrict__ S,        // (1024 i, 1024 j)
    __hip_bfloat16* __restrict__ xb)       // (16384,1024) bf16
{
    const int bx  = blockIdx.x;
    const int tid = threadIdx.x;
    __shared__ f4 h[2][N_DIM];  // ping-pong interleaved buffers, 32 KB

    if (bx >= 512) {  // ---- cast part ----
        const int cb = bx - 512;
        const size_t i = ((size_t)cb * 256 + tid) * 8;
        float4 v0 = *(const float4*)(x + i);
        float4 v1 = *(const float4*)(x + i + 4);
        union { __hip_bfloat16 e[8]; int4 v; } u;
        u.e[0] = __float2bfloat16(v0.x); u.e[1] = __float2bfloat16(v0.y);
        u.e[2] = __float2bfloat16(v0.z); u.e[3] = __float2bfloat16(v0.w);
        u.e[4] = __float2bfloat16(v1.x); u.e[5] = __float2bfloat16(v1.y);
        u.e[6] = __float2bfloat16(v1.z); u.e[7] = __float2bfloat16(v1.w);
        *(int4*)(xb + i) = u.v;
        return;
    }

    // ---- build part ----
    const int row0 = bx * 2;
    const f4 zz = {0.0f, 0.0f, 0.0f, 0.0f};
    for (int j = tid; j < N_DIM; j += 256) { h[0][j] = zz; h[1][j] = zz; }
    __syncthreads();
    if (tid == 0) {
        f4 e0 = {1.0f, 0.0f, 0.0f, 0.0f};
        f4 e1 = {0.0f, 0.0f, 1.0f, 0.0f};
        h[0][row0]     = e0;
        h[0][row0 + 1] = e1;
    }
    __syncthreads();

    int cur = 0;
    for (int d = 0; d < DEPTH; ++d) {
        const float p0 = 1.0f / (1.0f + expf(-perm_logit[d * 3 + 0]));
        const float p1 = 1.0f / (1.0f + expf(-perm_logit[d * 3 + 1]));
        const float p2 = 1.0f / (1.0f + expf(-perm_logit[d * 3 + 2]));

        // ---- perm factors, m = 4 .. 1024 (ascending) ----
#pragma unroll
        for (int s = 2; s <= 10; ++s) {
            if (s >= 8) __syncthreads();             // cross-wave mixing starts
            else        __builtin_amdgcn_wave_barrier();
            const int half = 1 << (s - 1), hq = half >> 1;
            const int cnt   = (d == 0) ? half : 512;
            const int pbase = (d == 0) ? ((row0 >> s) << (s - 1)) : 0;
            const f4* __restrict__ in = h[cur];
            f4* __restrict__ out      = h[cur ^ 1];
            for (int tt = tid; tt < cnt; tt += 256) {
                const int t    = pbase + tt;
                const int blk  = t >> (s - 1);
                const int r    = t & (half - 1);
                const int base = blk << s;
                int q1, q2; float pc;
                if (r < hq) { q1 = r;           q2 = half - 1 - r;   pc = p1; }
                else        { int r2 = r - hq;  q1 = half + r2;
                              q2 = 2 * half - 1 - r2;                pc = p2; }
                const int src1 = (q1 < half) ? 2 * q1 : 2 * (q1 - half) + 1;
                const int src2 = (q2 < half) ? 2 * q2 : 2 * (q2 - half) + 1;
                f4 b1 = in[base + q1], a1 = in[base + src1];
                f4 b2 = in[base + q2], a2 = in[base + src2];
                f4 s1a = b1 + p0 * (a1 - b1);
                f4 s1b = b2 + p0 * (a2 - b2);
                out[base + q1] = s1a + pc * (s1b - s1a);
                out[base + q2] = s1b + pc * (s1a - s1b);
            }
            cur ^= 1;
        }
        __syncthreads();  // perm s=10 output is block-wide

        // ---- diag factors fused in pairs: (1,2)..(9,10) ----
        const float* __restrict__ abd = abcd + (size_t)d * (ABCD_TOTAL * 2);
#pragma unroll
        for (int s = 1; s <= 9; s += 2) {
            if (s == 9) __syncthreads();             // (9,10) mixes across waves
            else        __builtin_amdgcn_wave_barrier();
            const int hh = 1 << (s - 1);
            const float* __restrict__ ab1 = abd + (size_t)(4096 - 8 * hh) * 2;
            const float* __restrict__ ab2 = abd + (size_t)(4096 - 16 * hh) * 2;
            const f4* __restrict__ in = h[cur];
            f4* __restrict__ out      = h[cur ^ 1];
            {
                const int g     = tid;
                const int k     = g & (hh - 1);
                const int base2 = (g >> (s - 1)) << (s + 1);
                f4 x0 = in[base2 + k];
                f4 x1 = in[base2 + k + hh];
                f4 x2 = in[base2 + k + 2 * hh];
                f4 x3 = in[base2 + k + 3 * hh];
                float2 A = *(const float2*)(ab1 + 2 * (size_t)k);
                float2 B = *(const float2*)(ab1 + 2 * (size_t)(hh + k));
                float2 C = *(const float2*)(ab1 + 2 * (size_t)(2 * hh + k));
                float2 D = *(const float2*)(ab1 + 2 * (size_t)(3 * hh + k));
                f4 y0 = cmul(A.x, A.y, x0) + cmul(B.x, B.y, x1);
                f4 y1 = cmul(C.x, C.y, x0) + cmul(D.x, D.y, x1);
                f4 y2 = cmul(A.x, A.y, x2) + cmul(B.x, B.y, x3);
                f4 y3 = cmul(C.x, C.y, x2) + cmul(D.x, D.y, x3);
                float2 A2 = *(const float2*)(ab2 + 2 * (size_t)k);
                float2 B2 = *(const float2*)(ab2 + 2 * (size_t)(2 * hh + k));
                float2 C2 = *(const float2*)(ab2 + 2 * (size_t)(4 * hh + k));
                float2 D2 = *(const float2*)(ab2 + 2 * (size_t)(6 * hh + k));
                float2 A3 = *(const float2*)(ab2 + 2 * (size_t)(hh + k));
                float2 B3 = *(const float2*)(ab2 + 2 * (size_t)(3 * hh + k));
                float2 C3 = *(const float2*)(ab2 + 2 * (size_t)(5 * hh + k));
                float2 D3 = *(const float2*)(ab2 + 2 * (size_t)(7 * hh + k));
                out[base2 + k]          = cmul(A2.x, A2.y, y0) + cmul(B2.x, B2.y, y2);
                out[base2 + k + 2 * hh] = cmul(C2.x, C2.y, y0) + cmul(D2.x, D2.y, y2);
                out[base2 + k + hh]     = cmul(A3.x, A3.y, y1) + cmul(B3.x, B3.y, y3);
                out[base2 + k + 3 * hh] = cmul(C3.x, C3.y, y1) + cmul(D3.x, D3.y, y3);
            }
            cur ^= 1;
        }
        __syncthreads();  // (9,10) output is block-wide
    }

    for (int j = tid; j < N_DIM; j += 256) {
        f4 v = h[cur][j];
        S[(size_t)row0 * N_DIM + j]       = __float2bfloat16(v[0]);
        S[(size_t)(row0 + 1) * N_DIM + j] = __float2bfloat16(v[2]);
    }
}

// ---------------------------------------------------------------------------
// Kernel 2: transpose S (i-major) -> Wt (j-major, contiguous k) via LDS tiles.
// (unchanged)
// ---------------------------------------------------------------------------
__global__ __launch_bounds__(256) void transpose_w(
    const __hip_bfloat16* __restrict__ S, __hip_bfloat16* __restrict__ Wt)
{
    const int i0 = (blockIdx.x & 15) * 64;
    const int j0 = (blockIdx.x >> 4) * 64;
    __shared__ __hip_bfloat16 tile[64][72];
    const int r  = threadIdx.x >> 2;
    const int c0 = (threadIdx.x & 3) * 16;
    *(short8*)&tile[r][c0]     = *(const short8*)(S + (size_t)(i0 + r) * N_DIM + j0 + c0);
    *(short8*)&tile[r][c0 + 8] = *(const short8*)(S + (size_t)(i0 + r) * N_DIM + j0 + c0 + 8);
    __syncthreads();
    union { __hip_bfloat16 e[8]; short8 v; } o1, o2;
#pragma unroll
    for (int k = 0; k < 8; ++k) { o1.e[k] = tile[c0 + k][r]; o2.e[k] = tile[c0 + 8 + k][r]; }
    *(short8*)(Wt + (size_t)(j0 + r) * N_DIM + i0 + c0)     = o1.v;
    *(short8*)(Wt + (size_t)(j0 + r) * N_DIM + i0 + c0 + 8) = o2.v;
}

// ---------------------------------------------------------------------------
// Kernel 3: out = xb(16384x1024 bf16) @ W + bias, fp32 out.
// 256x256 tile, BK=64, 8 waves (2Mx4N), 8-phase schedule with counted vmcnt
// (T3+T4), setprio around MFMA clusters (T5), chunk-XOR LDS swizzle applied
// on the global source side (T2-equivalent; LDS dest stays lane-linear for
// global_load_lds). 128 KiB LDS double-buffer, 1 block/CU.
//
// Phase map per iteration (tiles t0=2i [buf0], t1=2i+1 [buf1]):
//  ph0: rdA(b0,mq0)+rdB(b0,nq0) | stage A-h1(t0+1)->b1 | MFMA(0,0)
//  ph1: rdB(b0,nq1)             | stage B-h1(t0+1)->b1 | MFMA(0,1)
//  ph2: rdA(b0,mq1)             | stage B-h0(t0+2)->b0 | MFMA(1,0)
//  ph3: --                      | stage A-h0(t0+2)->b0 | MFMA(1,1) | vmcnt(4)
//  ph4: rdA(b1,mq0)+rdB(b1,nq0) | stage A-h1(t0+2)->b0 | MFMA(0,0)
//  ph5: rdB(b1,nq1)             | stage B-h1(t0+2)->b0 | MFMA(0,1)
//  ph6: rdA(b1,mq1)             | stage B-h0(t0+3)->b1 | MFMA(1,0)
//  ph7: --                      | stage A-h0(t0+3)->b1 | MFMA(1,1) | vmcnt(4)
// Every stage lands >=1 barrier after the last ds_read of the slot it
// overwrites; vmcnt(4)+barrier at each tile boundary guarantees data-ready.
// ---------------------------------------------------------------------------
__device__ __forceinline__ void gl_lds16(const void* g, void* l) {
    __builtin_amdgcn_global_load_lds(
        (const __attribute__((address_space(1))) uint32_t*)g,
        (__attribute__((address_space(3))) uint32_t*)l, 16, 0, 0);
}

#define GBAR  __builtin_amdgcn_s_barrier()
#define LGKM0 do { asm volatile("s_waitcnt lgkmcnt(0)" ::: "memory"); \
                   __builtin_amdgcn_sched_barrier(0); } while (0)
#define VM4   asm volatile("s_waitcnt vmcnt(4)" ::: "memory")
#define VM0   asm volatile("s_waitcnt vmcnt(0)" ::: "memory")
#define PRIO1 __builtin_amdgcn_s_setprio(1)
#define PRIO0 __builtin_amdgcn_s_setprio(0)

// stage one 128x64 half-tile (2 x global_load_lds dwordx4 per thread)
#define STG_A(kelem, h, buf) do { \
    gl_lds16(gA + (kelem) + (size_t)((h) * 128)      * N_DIM, sA + (buf) * 32768 + (h) * 16384 + tb); \
    gl_lds16(gA + (kelem) + (size_t)((h) * 128 + 64) * N_DIM, sA + (buf) * 32768 + (h) * 16384 + 8192 + tb); \
  } while (0)
#define STG_B(kelem, h, buf) do { \
    gl_lds16(gB + (kelem) + (size_t)((h) * 128)      * N_DIM, sB + (buf) * 32768 + (h) * 16384 + tb); \
    gl_lds16(gB + (kelem) + (size_t)((h) * 128 + 64) * N_DIM, sB + (buf) * 32768 + (h) * 16384 + 8192 + tb); \
  } while (0)

#define RD_A(buf, mq) do { \
    _Pragma("unroll") \
    for (int fi = 0; fi < 4; ++fi) { \
      af[fi][0] = *(const short8*)(aRd + (buf) * 32768 + (mq) * 8192 + fi * 2048 + cp0); \
      af[fi][1] = *(const short8*)(aRd + (buf) * 32768 + (mq) * 8192 + fi * 2048 + cp1); \
    } } while (0)

#define RD_B(buf, nq) do { \
    _Pragma("unroll") \
    for (int n = 0; n < 2; ++n) { \
      bf[nq][n][0] = *(const short8*)(bRd + (buf) * 32768 + ((nq) * 2 + n) * 2048 + cp0); \
      bf[nq][n][1] = *(const short8*)(bRd + (buf) * 32768 + ((nq) * 2 + n) * 2048 + cp1); \
    } } while (0)

#define MM16(mq, nq) do { \
    _Pragma("unroll") \
    for (int fi = 0; fi < 4; ++fi) { \
      _Pragma("unroll") \
      for (int n = 0; n < 2; ++n) { \
        acc[(mq) * 4 + fi][(nq) * 2 + n] = __builtin_amdgcn_mfma_f32_16x16x32_bf16( \
            af[fi][0], bf[nq][n][0], acc[(mq) * 4 + fi][(nq) * 2 + n], 0, 0, 0); \
        acc[(mq) * 4 + fi][(nq) * 2 + n] = __builtin_amdgcn_mfma_f32_16x16x32_bf16( \
            af[fi][1], bf[nq][n][1], acc[(mq) * 4 + fi][(nq) * 2 + n], 0, 0, 0); \
      } } } while (0)

__global__ __launch_bounds__(512, 2) void gemm_256(
    const __hip_bfloat16* __restrict__ A,   // (16384, 1024) bf16
    const __hip_bfloat16* __restrict__ Bt,  // (1024 n, 1024 k) bf16
    const float* __restrict__ bias,         // (1024)
    float* __restrict__ C)                  // (16384, 1024) f32
{
    __shared__ __attribute__((aligned(128))) char smem[131072];  // A: 64K, B: 64K

    const int t    = threadIdx.x;
    const int bid  = blockIdx.x;
    // XCD-aware swizzle: 8 m-tile panels + all 4 n-tiles per XCD (A panel set = 4 MB = L2)
    const int xcd  = bid & 7;
    const int loc  = bid >> 3;
    const int m0   = (xcd * 8 + (loc >> 2)) * 256;
    const int n0   = (loc & 3) * 256;

    const int lane = t & 63;
    const int wave = t >> 6;
    const int wm   = wave >> 2;   // 0..1  (M half)
    const int wn   = wave & 3;    // 0..3  (N quarter)
    const int lq   = lane >> 4;
    const int l15  = lane & 15;

    // staging: granule g = j*512 + t -> row g>>3 (0..127), phys chunk g&7.
    // logical chunk = phys ^ (row&7); row&7 == (t>>3)&7 for both j.
    const int r8 = t >> 3;
    const int cl = (t & 7) ^ (r8 & 7);
    const __hip_bfloat16* gA = A  + (size_t)(m0 + r8) * N_DIM + cl * 8;
    const __hip_bfloat16* gB = Bt + (size_t)(n0 + r8) * N_DIM + cl * 8;

    char* const sA = smem;
    char* const sB = smem + 65536;
    const int tb = t * 16;

    // fragment-read bases; phys chunk = (ks*4 + lq) ^ (lane&7)  -> 2-way banks (free)
    const char* aRd = smem + wm * 16384 + l15 * 128;
    const char* bRd = smem + 65536 + (wn >> 1) * 16384 + ((wn & 1) * 64 + l15) * 128;
    const int cp0 = ((lq)     ^ (lane & 7)) * 16;
    const int cp1 = ((4 + lq) ^ (lane & 7)) * 16;

    short8  af[4][2];        // A frags: 4 m-frags x 2 ks (current mq)
    short8  bf[2][2][2];     // B frags: nq x n x ks (both nq live)
    floatx4 acc[8][4] = {};  // 128 VGPRs

    // ---- prologue: tile0 all 4 halves, then tile1 {B-h0, A-h0} ----
    STG_A(0, 0, 0); STG_A(0, 1, 0); STG_B(0, 0, 0); STG_B(0, 1, 0);
    STG_B(64, 0, 1); STG_A(64, 0, 1);
    VM4;   // tile0's 8 loads drained; tile1's 4 still in flight
    GBAR;

    // ---- main loop: iterations 0..6 (tiles 0..13), steady-state staging ----
    for (int it = 0; it < 7; ++it) {
        const int k0 = it * 128;
        // ph0
        RD_A(0, 0); RD_B(0, 0);
        STG_A(k0 + 64, 1, 1);
        GBAR; LGKM0; PRIO1; MM16(0, 0); PRIO0; GBAR;
        // ph1
        RD_B(0, 1);
        STG_B(k0 + 64, 1, 1);
        GBAR; LGKM0; PRIO1; MM16(0, 1); PRIO0; GBAR;
        // ph2
        RD_A(0, 1);
        STG_B(k0 + 128, 0, 0);
        GBAR; LGKM0; PRIO1; MM16(1, 0); PRIO0; GBAR;
        // ph3
        STG_A(k0 + 128, 0, 0);
        GBAR; LGKM0; PRIO1; MM16(1, 1); PRIO0; VM4; GBAR;
        // ph4
        RD_A(1, 0); RD_B(1, 0);
        STG_A(k0 + 128, 1, 0);
        GBAR; LGKM0; PRIO1; MM16(0, 0); PRIO0; GBAR;
        // ph5
        RD_B(1, 1);
        STG_B(k0 + 128, 1, 0);
        GBAR; LGKM0; PRIO1; MM16(0, 1); PRIO0; GBAR;
        // ph6
        RD_A(1, 1);
        STG_B(k0 + 192, 0, 1);
        GBAR; LGKM0; PRIO1; MM16(1, 0); PRIO0; GBAR;
        // ph7
        STG_A(k0 + 192, 0, 1);
        GBAR; LGKM0; PRIO1; MM16(1, 1); PRIO0; VM4; GBAR;
    }

    // ---- peeled final iteration (tiles 14, 15): no further staging ----
    {
        // ph0: stage tile15 A-h1 (last A half)
        RD_A(0, 0); RD_B(0, 0);
        STG_A(896 + 64, 1, 1);
        GBAR; LGKM0; PRIO1; MM16(0, 0); PRIO0; GBAR;
        // ph1: stage tile15 B-h1 (last load of the kernel)
        RD_B(0, 1);
        STG_B(896 + 64, 1, 1);
        GBAR; LGKM0; PRIO1; MM16(0, 1); PRIO0; GBAR;
        // ph2
        RD_A(0, 1);
        GBAR; LGKM0; PRIO1; MM16(1, 0); PRIO0; GBAR;
        // ph3: drain everything (tile15 halves) before its reads
        GBAR; LGKM0; PRIO1; MM16(1, 1); PRIO0; VM0; GBAR;
        // ph4
        RD_A(1, 0); RD_B(1, 0);
        GBAR; LGKM0; PRIO1; MM16(0, 0); PRIO0; GBAR;
        // ph5
        RD_B(1, 1);
        GBAR; LGKM0; PRIO1; MM16(0, 1); PRIO0; GBAR;
        // ph6
        RD_A(1, 1);
        GBAR; LGKM0; PRIO1; MM16(1, 0); PRIO0; GBAR;
        // ph7
        PRIO1; MM16(1, 1); PRIO0;
    }

    // ---- epilogue: C = acc + bias ----
#pragma unroll
    for (int f = 0; f < 8; ++f) {
        const int gm = m0 + wm * 128 + f * 16 + lq * 4;
#pragma unroll
        for (int nf = 0; nf < 4; ++nf) {
            const int gn = n0 + wn * 64 + nf * 16 + l15;
            const float bv = bias[gn];
#pragma unroll
            for (int r = 0; r < 4; ++r)
                C[(size_t)(gm + r) * N_DIM + gn] = acc[f][nf][r] + bv;
        }
    }
}

// ---------------------------------------------------------------------------
extern "C" void kernel_launch(void* const* d_in, const int* in_sizes, int n_in,
                              void* d_out, int out_size, void* d_ws, size_t ws_size,
                              hipStream_t stream) {
    const float* x          = (const float*)d_in[0];
    const float* perm_logit = (const float*)d_in[1];
    const float* abcd       = (const float*)d_in[2];
    const float* bias       = (const float*)d_in[3];
    float* out              = (float*)d_out;

    // S (2 MB) lives in d_out scratch space (gemm overwrites d_out afterward).
    __hip_bfloat16* S  = (__hip_bfloat16*)d_out;
    __hip_bfloat16* Wt = (__hip_bfloat16*)d_ws;                      // 2 MB
    __hip_bfloat16* xb = (__hip_bfloat16*)((char*)d_ws + (1 << 21)); // 32 MB

    build_and_cast<<<dim3(512 + 8192), dim3(256), 0, stream>>>(perm_logit, abcd, x, S, xb);
    transpose_w<<<dim3(256), dim3(256), 0, stream>>>(S, Wt);
    gemm_256<<<dim3(256), dim3(512), 0, stream>>>(xb, Wt, bias, out);
}